// Round 1
// baseline (37.689 us; speedup 1.0000x reference)
//
#include <hip/hip_runtime.h>

// CorrLookup: RAFT-style correlation-pyramid lookup.
// B=8, H=96, W=256, N=B*H*W=196608, R=4, K=9, 4 levels, Wi = 256>>lvl.
// out[b, lvl*9+k, h, w] = linear-interp of corr_lvl[row n] at x = (k-4) + disp/2^lvl,
// zeros padding for OOB taps.

#define RADIUS 4
#define KTAPS 9

__global__ __launch_bounds__(256) void corr_lookup_kernel(
    const float* __restrict__ corr0,
    const float* __restrict__ corr1,
    const float* __restrict__ corr2,
    const float* __restrict__ corr3,
    const float* __restrict__ flow,
    float* __restrict__ out,
    int HW, int N)
{
    int n = blockIdx.x * blockDim.x + threadIdx.x;
    if (n >= N) return;

    int b   = n / HW;          // batch
    int rem = n - b * HW;      // h*W + w within the image

    // flow layout: (B, 2, H, W); channel 0 = disparity
    float disp = flow[(size_t)b * 2 * HW + rem];

    const float* const corrs[4] = {corr0, corr1, corr2, corr3};

    // out layout: (B, 36, H, W)
    size_t out_base = (size_t)b * 36 * HW + (size_t)rem;

#pragma unroll
    for (int lvl = 0; lvl < 4; ++lvl) {
        const int Wi = 256 >> lvl;
        // exact: multiply by 2^-lvl == divide by 2^lvl
        const float scale = 1.0f / (float)(1 << lvl);
        float t  = disp * scale;
        float fb = floorf(t);
        float w  = t - fb;          // shared fractional weight for all 9 taps
        int   ib = (int)fb;

        const float* row = corrs[lvl] + (size_t)n * (size_t)Wi;

        // contiguous span of 10 values: indices ib-4 .. ib+5, zeros for OOB
        float v[KTAPS + 1];
#pragma unroll
        for (int j = 0; j <= KTAPS; ++j) {
            int idx = ib - RADIUS + j;
            v[j] = (idx >= 0 && idx < Wi) ? row[idx] : 0.0f;
        }

#pragma unroll
        for (int k = 0; k < KTAPS; ++k) {
            float val = (1.0f - w) * v[k] + w * v[k + 1];
            out[out_base + (size_t)(lvl * KTAPS + k) * (size_t)HW] = val;
        }
    }
}

extern "C" void kernel_launch(void* const* d_in, const int* in_sizes, int n_in,
                              void* d_out, int out_size, void* d_ws, size_t ws_size,
                              hipStream_t stream)
{
    const float* corr0 = (const float*)d_in[0];
    const float* corr1 = (const float*)d_in[1];
    const float* corr2 = (const float*)d_in[2];
    const float* corr3 = (const float*)d_in[3];
    const float* flow  = (const float*)d_in[4];
    float* out = (float*)d_out;

    // flow is (B,2,H,W): N = B*H*W = in_sizes[4]/2
    const int N  = in_sizes[4] / 2;
    const int B  = 8;
    const int HW = N / B;   // 96*256 = 24576

    dim3 block(256);
    dim3 grid((N + 255) / 256);
    hipLaunchKernelGGL(corr_lookup_kernel, grid, block, 0, stream,
                       corr0, corr1, corr2, corr3, flow, out, HW, N);
}